// Round 2
// baseline (11.841 us; speedup 1.0000x reference)
//
#include <hip/hip_runtime.h>

// Problem: Q=32, V=50000, F=256, C=10
//   out[q,c,f] = (labels[q,c] != 2 ? pe[q, ids[q,c], f] : 0)
//              + interaction_embeddings[labels[q,c], f]
// Output: [Q, C, F] fp32 = 81920 elements (327 KB).
//
// One wave per (q,c) row (320 waves). Row index is wave-uniform, so force
// ids/labels through scalar loads (readfirstlane) to shorten the dependent
// vector-load chain. Each lane handles one float4 (lane*16B) of the 1 KB row.

constexpr int Q = 32;
constexpr int V = 50000;
constexpr int F = 256;
constexpr int C = 10;
constexpr int ROWS = Q * C;             // 320 waves
constexpr int THREADS = ROWS * 64;      // 20480

__global__ __launch_bounds__(256) void click_embed_kernel(
    const float* __restrict__ pe,        // [Q, V, F]
    const int*   __restrict__ ids,       // [Q, C]
    const int*   __restrict__ labels,    // [Q, C]
    const float* __restrict__ emb,       // [3, F]
    float*       __restrict__ out)       // [Q, C, F]
{
    int tid  = blockIdx.x * blockDim.x + threadIdx.x;
    int lane = threadIdx.x & 63;
    int row  = __builtin_amdgcn_readfirstlane(tid >> 6);   // q*C + c, in SGPR

    int label = labels[row];             // scalar load (uniform addr)
    int id    = ids[row];                // scalar load (uniform addr)
    int q     = row / C;

    // Each lane: float4 #lane of the 256-float row.
    const float4* embv = reinterpret_cast<const float4*>(emb);
    float4 e = embv[label * 64 + lane];

    if (label != 2) {                    // wave-uniform branch (s_cbranch)
        long long src = ((long long)q * V + id) * 64 + lane;
        float4 g = reinterpret_cast<const float4*>(pe)[src];
        e.x += g.x; e.y += g.y; e.z += g.z; e.w += g.w;
    }

    reinterpret_cast<float4*>(out)[(long long)row * 64 + lane] = e;
}

extern "C" void kernel_launch(void* const* d_in, const int* in_sizes, int n_in,
                              void* d_out, int out_size, void* d_ws, size_t ws_size,
                              hipStream_t stream) {
    const float* pe     = (const float*)d_in[0];
    const int*   ids    = (const int*)d_in[1];
    const int*   labels = (const int*)d_in[2];
    const float* emb    = (const float*)d_in[3];
    float*       out    = (float*)d_out;

    dim3 block(256);
    dim3 grid(THREADS / 256);            // 80 blocks
    click_embed_kernel<<<grid, block, 0, stream>>>(pe, ids, labels, emb, out);
}

// Round 3
// 9.340 us; speedup vs baseline: 1.2677x; 1.2677x over previous
//
#include <hip/hip_runtime.h>

// Problem: Q=32, V=50000, F=256, C=10
//   out[q,c,f] = (labels[q,c] != 2 ? pe[q, ids[q,c], f] : 0)
//              + interaction_embeddings[labels[q,c], f]
// Output: [Q, C, F] fp32 = 81920 elements (327 KB).
//
// Launch-overhead-bound (~1 MB effective traffic, L2-resident gathers).
// One float4 per thread, coalesced; 32-bit indexing throughout
// (max gather element index = 32*50000*64 ≈ 102.4M < 2^31; byte offset
// 1.6 GB < 2^31).

constexpr int Q = 32;
constexpr int V = 50000;
constexpr int F = 256;
constexpr int C = 10;
constexpr int F4 = F / 4;               // 64 float4 per row
constexpr int TOTAL4 = Q * C * F4;      // 20480 threads

__global__ __launch_bounds__(256) void click_embed_kernel(
    const float* __restrict__ pe,        // [Q, V, F]
    const int*   __restrict__ ids,       // [Q, C]
    const int*   __restrict__ labels,    // [Q, C]
    const float* __restrict__ emb,       // [3, F]
    float*       __restrict__ out)       // [Q, C, F]
{
    int idx = blockIdx.x * blockDim.x + threadIdx.x;

    int f4  = idx & (F4 - 1);            // float4 index within row
    int row = idx >> 6;                  // q*C + c  (F4 == 64), wave-uniform
    int q   = row / C;

    int label = labels[row];
    int id    = ids[row];

    const float4* embv = reinterpret_cast<const float4*>(emb);
    float4 e = embv[label * F4 + f4];

    if (label != 2) {                    // wave-uniform branch
        int src = (q * V + id) * F4 + f4;   // fits in int32
        float4 g = reinterpret_cast<const float4*>(pe)[src];
        e.x += g.x; e.y += g.y; e.z += g.z; e.w += g.w;
    }

    reinterpret_cast<float4*>(out)[idx] = e;
}

extern "C" void kernel_launch(void* const* d_in, const int* in_sizes, int n_in,
                              void* d_out, int out_size, void* d_ws, size_t ws_size,
                              hipStream_t stream) {
    const float* pe     = (const float*)d_in[0];
    const int*   ids    = (const int*)d_in[1];
    const int*   labels = (const int*)d_in[2];
    const float* emb    = (const float*)d_in[3];
    float*       out    = (float*)d_out;

    dim3 block(256);
    dim3 grid(TOTAL4 / 256);             // 80 blocks, exact
    click_embed_kernel<<<grid, block, 0, stream>>>(pe, ids, labels, emb, out);
}